// Round 3
// baseline (440.716 us; speedup 1.0000x reference)
//
#include <hip/hip_runtime.h>
#include <stdint.h>

// ---------------------------------------------------------------------------
// Sparse attention, MI355X. I/O contract (per reference dtypes): inputs are
// FLOAT32 (mask int32), output FLOAT32. Internally convert to bf16 once and
// run the MFMA pipeline:
//   0) xb = bf16(x); Wvb/Wqgb/Wkgb/Wob = bf16(weight slices)
//   1) qkv[:, :512] = xb @ Wvb[:512]^T + bv[:512]    (local heads = V)
//   2) vg = xb @ Wvb[512:]^T + bv[512:]              (16384 x 512)
//   3) qg = xb @ Wqgb^T + bq[512:]                   (16384 x 512)
//   4) kg = xb @ Wkgb^T + bk[512:]                   (16384 x 512)
//   5) qkv[:, 512:] = sparse_attention(qg, kg, vg, mask)
//   6) out(f32) = qkv @ Wob^T + bo
// ---------------------------------------------------------------------------

typedef __bf16 bf16_t;
typedef __bf16 bf16x4 __attribute__((ext_vector_type(4)));
typedef __bf16 bf16x8 __attribute__((ext_vector_type(8)));
typedef float floatx4 __attribute__((ext_vector_type(4)));

#define MFMA16(a, b, c) __builtin_amdgcn_mfma_f32_16x16x32_bf16((a), (b), (c), 0, 0, 0)

// ---------------------------------------------------------------------------
// f32 -> bf16 conversion, 4 elems/thread (float4 load, 8B store)
// ---------------------------------------------------------------------------
__global__ void cvt_f32_bf16(const float* __restrict__ src, bf16_t* __restrict__ dst, int n) {
  const int i = (blockIdx.x * 256 + threadIdx.x) * 4;
  if (i < n) {
    float4 v = *(const float4*)(src + i);
    bf16x4 d = {(bf16_t)v.x, (bf16_t)v.y, (bf16_t)v.z, (bf16_t)v.w};
    *(bf16x4*)(dst + i) = d;
  }
}

// ---------------------------------------------------------------------------
// C = A @ W^T + bias.  A: (M x 1024) bf16, W: (N x 1024) bf16 (K-contiguous),
// bias f32, C: (M x ldc) OutT.  128x128 tile, BK=32, 4 waves each 64x64,
// 16x16x32 bf16 MFMA.  LDS frag order: chunk id = q*128 + m -> [m][8q..8q+7].
// Register staging (m92/m93 verified path).
// ---------------------------------------------------------------------------
template <typename OutT>
__global__ __launch_bounds__(256, 2)
void gemm_bt(const bf16_t* __restrict__ A, const bf16_t* __restrict__ W,
             const float* __restrict__ bias, OutT* __restrict__ C, int ldc) {
  __shared__ bf16_t As[4096];  // 128 rows x 32 k, frag-ordered, 8 KiB
  __shared__ bf16_t Bs[4096];

  const int tid = threadIdx.x;
  const int w = tid >> 6, l = tid & 63;
  const int lq = l >> 4, lm = l & 15;
  const long row0 = (long)blockIdx.y * 128;
  const long col0 = (long)blockIdx.x * 128;
  const int wr = (w >> 1) << 6;  // wave quadrant rows 0/64
  const int wc = (w & 1) << 6;   // wave quadrant cols 0/64

  floatx4 zero4 = {0.f, 0.f, 0.f, 0.f};
  floatx4 acc[4][4];
#pragma unroll
  for (int i = 0; i < 4; ++i)
#pragma unroll
    for (int j = 0; j < 4; ++j) acc[i][j] = zero4;

  // staging: 512 chunks per tile; thread t handles chunks t and t+256
  const int id0 = tid;
  const int id1 = tid + 256;
  const int q0 = id0 >> 7, m0 = id0 & 127;
  const int q1 = id1 >> 7, m1 = id1 & 127;
  const bf16_t* ga0 = A + (row0 + m0) * 1024 + q0 * 8;
  const bf16_t* ga1 = A + (row0 + m1) * 1024 + q1 * 8;
  const bf16_t* gb0 = W + (col0 + m0) * 1024 + q0 * 8;
  const bf16_t* gb1 = W + (col0 + m1) * 1024 + q1 * 8;

  for (int kt = 0; kt < 32; ++kt) {
    bf16x8 va0 = *(const bf16x8*)ga0; ga0 += 32;
    bf16x8 va1 = *(const bf16x8*)ga1; ga1 += 32;
    bf16x8 vb0 = *(const bf16x8*)gb0; gb0 += 32;
    bf16x8 vb1 = *(const bf16x8*)gb1; gb1 += 32;

    __syncthreads();  // prev iteration's frag reads complete before overwrite
    *(bf16x8*)(As + id0 * 8) = va0;
    *(bf16x8*)(As + id1 * 8) = va1;
    *(bf16x8*)(Bs + id0 * 8) = vb0;
    *(bf16x8*)(Bs + id1 * 8) = vb1;
    __syncthreads();  // staging visible to all waves

    bf16x8 af[4], bfr[4];
#pragma unroll
    for (int mt = 0; mt < 4; ++mt)
      af[mt] = *(const bf16x8*)(As + (lq * 128 + wr + mt * 16 + lm) * 8);
#pragma unroll
    for (int nt = 0; nt < 4; ++nt)
      bfr[nt] = *(const bf16x8*)(Bs + (lq * 128 + wc + nt * 16 + lm) * 8);
#pragma unroll
    for (int mt = 0; mt < 4; ++mt)
#pragma unroll
      for (int nt = 0; nt < 4; ++nt)
        acc[mt][nt] = MFMA16(af[mt], bfr[nt], acc[mt][nt]);
  }

  // epilogue: C/D layout col=lane&15, row=(lane>>4)*4+reg  [m89-verified]
#pragma unroll
  for (int nt = 0; nt < 4; ++nt) {
    const long col = col0 + wc + nt * 16 + lm;
    const float bc = bias[col];
#pragma unroll
    for (int mt = 0; mt < 4; ++mt) {
#pragma unroll
      for (int r = 0; r < 4; ++r) {
        const long row = row0 + wr + mt * 16 + lq * 4 + r;
        C[row * (long)ldc + col] = (OutT)(acc[mt][nt][r] + bc);
      }
    }
  }
}

// ---------------------------------------------------------------------------
// Sparse attention for global heads. Block = (qt, h, b): 64 query rows,
// 256 selected keys: token(l) = 64*(l>>2) + 32 + 4*h + (l&3).
// 4 waves x 16 query rows each. QK^T and PV via 16x16x32 bf16 MFMA.
// ---------------------------------------------------------------------------
__global__ __launch_bounds__(256, 1)
void attn_sparse(const bf16_t* __restrict__ qg, const bf16_t* __restrict__ kg,
                 const bf16_t* __restrict__ vg, const int* __restrict__ mask,
                 bf16_t* __restrict__ qkv) {
  __shared__ bf16_t Ks[16384];        // frag-order: chunk = kq*256 + lkey
  __shared__ bf16_t Vt[64 * 264];     // Vt[d][lkey], row stride 264 (+8 pad)
  __shared__ bf16_t Ps[4 * 16 * 136]; // per-wave P half-tile, stride 136 (+8 pad)
  __shared__ int smask[256];

  const int tid = threadIdx.x;
  const int b = blockIdx.z, h = blockIdx.y, qt = blockIdx.x;

  // ---- stage K rows, V columns (transposed), mask
  {
    const int lk = tid;  // key slot 0..255
    const int token = ((lk >> 2) << 6) + 32 + (h << 2) + (lk & 3);
    const size_t rowi = (size_t)(b * 4096 + token);
    const uint4* ksrc = (const uint4*)(kg + rowi * 512 + h * 64);
#pragma unroll
    for (int kq = 0; kq < 8; ++kq)
      *(uint4*)(Ks + (kq * 256 + lk) * 8) = ksrc[kq];
    const bf16_t* vsrc = vg + rowi * 512 + h * 64;
#pragma unroll
    for (int i = 0; i < 8; ++i) {
      bf16x8 vv = *(const bf16x8*)(vsrc + i * 8);
#pragma unroll
      for (int j = 0; j < 8; ++j) Vt[(i * 8 + j) * 264 + lk] = vv[j];
    }
    smask[lk] = mask[b * 4096 + token];
  }
  __syncthreads();

  const int w = tid >> 6, l = tid & 63, lq = l >> 4, lm = l & 15;
  const int mrow = (qt << 6) + (w << 4);  // first query token of this wave

  // A fragments of Q (K-dim 64 = 2 mfma k-chunks), straight from global
  const bf16_t* qrow = qg + (size_t)(b * 4096 + mrow + lm) * 512 + h * 64 + lq * 8;
  bf16x8 aq0 = *(const bf16x8*)qrow;
  bf16x8 aq1 = *(const bf16x8*)(qrow + 32);

  // ---- S = Q K^T  (16 rows x 256 cols per wave)
  floatx4 zero4 = {0.f, 0.f, 0.f, 0.f};
  floatx4 s[16];
#pragma unroll
  for (int t = 0; t < 16; ++t) {
    bf16x8 kb0 = *(const bf16x8*)(Ks + (lq * 256 + t * 16 + lm) * 8);
    bf16x8 kb1 = *(const bf16x8*)(Ks + ((4 + lq) * 256 + t * 16 + lm) * 8);
    floatx4 z = zero4;
    z = MFMA16(aq0, kb0, z);
    z = MFMA16(aq1, kb1, z);
    s[t] = z;
  }

  // ---- scale + mask + softmax (rows lq*4+r, fp32)
  float rmax[4] = {-1e30f, -1e30f, -1e30f, -1e30f};
#pragma unroll
  for (int t = 0; t < 16; ++t) {
    const bool mk = smask[t * 16 + lm] != 0;
#pragma unroll
    for (int r = 0; r < 4; ++r) {
      float v = s[t][r] * 0.125f;  // KD^-0.5 = 1/8
      v = mk ? -1e10f : v;
      s[t][r] = v;
      rmax[r] = fmaxf(rmax[r], v);
    }
  }
#pragma unroll
  for (int off = 1; off < 16; off <<= 1)
#pragma unroll
    for (int r = 0; r < 4; ++r) rmax[r] = fmaxf(rmax[r], __shfl_xor(rmax[r], off));
  float rsum[4] = {0.f, 0.f, 0.f, 0.f};
#pragma unroll
  for (int t = 0; t < 16; ++t)
#pragma unroll
    for (int r = 0; r < 4; ++r) {
      float p = __expf(s[t][r] - rmax[r]);
      s[t][r] = p;
      rsum[r] += p;
    }
#pragma unroll
  for (int off = 1; off < 16; off <<= 1)
#pragma unroll
    for (int r = 0; r < 4; ++r) rsum[r] += __shfl_xor(rsum[r], off);
  float rinv[4];
#pragma unroll
  for (int r = 0; r < 4; ++r) rinv[r] = 1.0f / rsum[r];

  // ---- O = P V, P routed through LDS (C-layout -> A-layout), 128-col halves
  floatx4 o[4];
#pragma unroll
  for (int dt = 0; dt < 4; ++dt) o[dt] = zero4;
  bf16_t* Pw = Ps + w * (16 * 136);
#pragma unroll
  for (int half = 0; half < 2; ++half) {
#pragma unroll
    for (int t = 0; t < 8; ++t) {
      const int tt = half * 8 + t;
#pragma unroll
      for (int r = 0; r < 4; ++r)
        Pw[(lq * 4 + r) * 136 + t * 16 + lm] = (bf16_t)(s[tt][r] * rinv[r]);
    }
    __syncthreads();
#pragma unroll
    for (int ks = 0; ks < 4; ++ks) {
      bf16x8 pa = *(const bf16x8*)(Pw + lm * 136 + ks * 32 + lq * 8);
#pragma unroll
      for (int dt = 0; dt < 4; ++dt) {
        bf16x8 vb = *(const bf16x8*)(Vt + (dt * 16 + lm) * 264 + half * 128 + ks * 32 + lq * 8);
        o[dt] = MFMA16(pa, vb, o[dt]);
      }
    }
    __syncthreads();
  }

  // ---- write g_out into qkv[:, 512 + h*64 + d]
#pragma unroll
  for (int dt = 0; dt < 4; ++dt) {
    const int d = dt * 16 + lm;
#pragma unroll
    for (int r = 0; r < 4; ++r) {
      const int token = mrow + lq * 4 + r;
      qkv[(size_t)(b * 4096 + token) * 1024 + 512 + h * 64 + d] = (bf16_t)o[dt][r];
    }
  }
}

// ---------------------------------------------------------------------------
extern "C" void kernel_launch(void* const* d_in, const int* in_sizes, int n_in,
                              void* d_out, int out_size, void* d_ws, size_t ws_size,
                              hipStream_t stream) {
  const float* x   = (const float*)d_in[0];
  const int* mask  = (const int*)d_in[1];
  const float* Wq  = (const float*)d_in[2];
  const float* bq  = (const float*)d_in[3];
  const float* Wk  = (const float*)d_in[4];
  const float* bk  = (const float*)d_in[5];
  const float* Wv  = (const float*)d_in[6];
  const float* bv  = (const float*)d_in[7];
  const float* Wo  = (const float*)d_in[8];
  const float* bo  = (const float*)d_in[9];
  float* out = (float*)d_out;

  // workspace layout (bytes), total 118 MB:
  //   xb 32MB | Wvb 2MB | Wqgb 1MB | Wkgb 1MB | Wob 2MB | vg 16 | qg 16 | kg 16 | qkv 32
  char* ws = (char*)d_ws;
  bf16_t* xb   = (bf16_t*)(ws);
  bf16_t* Wvb  = (bf16_t*)(ws + 33554432L);
  bf16_t* Wqgb = (bf16_t*)(ws + 35651584L);
  bf16_t* Wkgb = (bf16_t*)(ws + 36700160L);
  bf16_t* Wob  = (bf16_t*)(ws + 37748736L);
  bf16_t* vg   = (bf16_t*)(ws + 39845888L);
  bf16_t* qg   = (bf16_t*)(ws + 56623104L);
  bf16_t* kg   = (bf16_t*)(ws + 73400320L);
  bf16_t* qkv  = (bf16_t*)(ws + 90177536L);

  dim3 blk(256);
  cvt_f32_bf16<<<16384, blk, 0, stream>>>(x, xb, 16777216);            // x: 16384x1024
  cvt_f32_bf16<<<1024, blk, 0, stream>>>(Wv, Wvb, 1048576);            // Wv full
  cvt_f32_bf16<<<512, blk, 0, stream>>>(Wq + 524288, Wqgb, 524288);    // Wq rows 512..1023
  cvt_f32_bf16<<<512, blk, 0, stream>>>(Wk + 524288, Wkgb, 524288);    // Wk rows 512..1023
  cvt_f32_bf16<<<1024, blk, 0, stream>>>(Wo, Wob, 1048576);            // Wo full

  gemm_bt<bf16_t><<<dim3(4, 128), blk, 0, stream>>>(xb, Wvb, bv, qkv, 1024);               // local V -> qkv[:, :512]
  gemm_bt<bf16_t><<<dim3(4, 128), blk, 0, stream>>>(xb, Wvb + 524288, bv + 512, vg, 512);  // global V
  gemm_bt<bf16_t><<<dim3(4, 128), blk, 0, stream>>>(xb, Wqgb, bq + 512, qg, 512);          // global Q
  gemm_bt<bf16_t><<<dim3(4, 128), blk, 0, stream>>>(xb, Wkgb, bk + 512, kg, 512);          // global K
  attn_sparse<<<dim3(64, 8, 4), blk, 0, stream>>>(qg, kg, vg, mask, qkv);
  gemm_bt<float><<<dim3(8, 128), blk, 0, stream>>>(qkv, Wob, bo, out, 1024);               // out projection (f32)
}

// Round 4
// 424.738 us; speedup vs baseline: 1.0376x; 1.0376x over previous
//
#include <hip/hip_runtime.h>
#include <stdint.h>

// ---------------------------------------------------------------------------
// Sparse attention, MI355X. f32 I/O, bf16 MFMA internals.
//   0) xb = bf16(x); Wcat = bf16([Wv; Wq[512:]; Wk[512:]]); Wob = bf16(Wo);
//      bcat = [bv; bq[512:]; bk[512:]]
//   1) fused proj GEMM: [qkv[:,:512] | vg | qg | kg] = xb @ Wcat^T + bcat
//   2) qkv[:, 512:] = sparse_attention(qg, kg, vg, mask)
//   3) out(f32) = qkv @ Wob^T + bo
// GEMMs use global_load_lds width-16 DMA staging (m97 path).
// ---------------------------------------------------------------------------

typedef __bf16 bf16_t;
typedef __bf16 bf16x4 __attribute__((ext_vector_type(4)));
typedef __bf16 bf16x8 __attribute__((ext_vector_type(8)));
typedef float floatx4 __attribute__((ext_vector_type(4)));

#define MFMA16(a, b, c) __builtin_amdgcn_mfma_f32_16x16x32_bf16((a), (b), (c), 0, 0, 0)

// async global->LDS, 16B per lane; LDS dest = wave-uniform base + lane*16
__device__ __forceinline__ void glds16(const bf16_t* g, const bf16_t* lds_base) {
  __builtin_amdgcn_global_load_lds(
      (const __attribute__((address_space(1))) uint32_t*)(uintptr_t)g,
      (__attribute__((address_space(3))) uint32_t*)(uintptr_t)lds_base, 16, 0, 0);
}

// ---------------------------------------------------------------------------
// f32 -> bf16 conversion, 4 elems/thread
// ---------------------------------------------------------------------------
__global__ void cvt_f32_bf16(const float* __restrict__ src, bf16_t* __restrict__ dst, int n) {
  const int i = (blockIdx.x * 256 + threadIdx.x) * 4;
  if (i < n) {
    float4 v = *(const float4*)(src + i);
    bf16x4 d = {(bf16_t)v.x, (bf16_t)v.y, (bf16_t)v.z, (bf16_t)v.w};
    *(bf16x4*)(dst + i) = d;
  }
}

// bcat = [bv(1024); bq[512:](512); bk[512:](512)]  (f32, 2048)
__global__ void pack_bias(const float* __restrict__ bv, const float* __restrict__ bq,
                          const float* __restrict__ bk, float* __restrict__ bcat) {
  const int i = blockIdx.x * 256 + threadIdx.x;  // 2048 threads
  float v;
  if (i < 1024) v = bv[i];
  else if (i < 1536) v = bq[i - 512];   // bq[512 + (i-1024)]
  else v = bk[i - 1024];                // bk[512 + (i-1536)]
  bcat[i] = v;
}

// ---------------------------------------------------------------------------
// Shared GEMM core macro-free: both kernels below use identical staging +
// MFMA loop. A: (M x 1024) bf16, W: (N x 1024) bf16 K-contiguous.
// 128x128 tile, BK=32, 4 waves each 64x64.  LDS frag order: chunk = q*128+m.
// DMA staging: 4 waves x 2 rounds x 64 lanes x 16B per buffer.
// ---------------------------------------------------------------------------
#define GEMM_CORE(A_, W_)                                                      \
  __shared__ bf16_t As[4096];                                                  \
  __shared__ bf16_t Bs[4096];                                                  \
  const int tid = threadIdx.x;                                                 \
  const int w = tid >> 6, l = tid & 63;                                        \
  const int lq = l >> 4, lm = l & 15;                                          \
  const long row0 = (long)blockIdx.y * 128;                                    \
  const long col0 = (long)blockIdx.x * 128;                                    \
  const int wr = (w >> 1) << 6;                                                \
  const int wc = (w & 1) << 6;                                                 \
  floatx4 zero4 = {0.f, 0.f, 0.f, 0.f};                                        \
  floatx4 acc[4][4];                                                           \
  _Pragma("unroll") for (int i = 0; i < 4; ++i)                                \
      _Pragma("unroll") for (int j = 0; j < 4; ++j) acc[i][j] = zero4;         \
  const int id0 = w * 64 + l;                                                  \
  const int id1 = id0 + 256;                                                   \
  const int q0 = id0 >> 7, m0 = id0 & 127;                                     \
  const int q1 = id1 >> 7, m1 = id1 & 127;                                     \
  const bf16_t* ga0 = (A_) + (row0 + m0) * 1024 + q0 * 8;                      \
  const bf16_t* ga1 = (A_) + (row0 + m1) * 1024 + q1 * 8;                      \
  const bf16_t* gb0 = (W_) + (col0 + m0) * 1024 + q0 * 8;                      \
  const bf16_t* gb1 = (W_) + (col0 + m1) * 1024 + q1 * 8;                      \
  const bf16_t* lA0 = As + (w * 64) * 8;                                       \
  const bf16_t* lA1 = As + (256 + w * 64) * 8;                                 \
  const bf16_t* lB0 = Bs + (w * 64) * 8;                                       \
  const bf16_t* lB1 = Bs + (256 + w * 64) * 8;                                 \
  for (int kt = 0; kt < 32; ++kt) {                                            \
    glds16(ga0, lA0);                                                          \
    glds16(ga1, lA1);                                                          \
    glds16(gb0, lB0);                                                          \
    glds16(gb1, lB1);                                                          \
    ga0 += 32; ga1 += 32; gb0 += 32; gb1 += 32;                                \
    __syncthreads();                                                           \
    bf16x8 af[4], bfr[4];                                                      \
    _Pragma("unroll") for (int mt = 0; mt < 4; ++mt)                           \
        af[mt] = *(const bf16x8*)(As + (lq * 128 + wr + mt * 16 + lm) * 8);    \
    _Pragma("unroll") for (int nt = 0; nt < 4; ++nt)                           \
        bfr[nt] = *(const bf16x8*)(Bs + (lq * 128 + wc + nt * 16 + lm) * 8);   \
    _Pragma("unroll") for (int mt = 0; mt < 4; ++mt)                           \
        _Pragma("unroll") for (int nt = 0; nt < 4; ++nt)                       \
            acc[mt][nt] = MFMA16(af[mt], bfr[nt], acc[mt][nt]);                \
    __syncthreads();                                                           \
  }

// out-projection (and generic) GEMM: C = A @ W^T + bias
template <typename OutT>
__global__ __launch_bounds__(256, 2)
void gemm_bt(const bf16_t* __restrict__ A, const bf16_t* __restrict__ W,
             const float* __restrict__ bias, OutT* __restrict__ C, int ldc) {
  GEMM_CORE(A, W)
  // epilogue: C/D layout col=lane&15, row=(lane>>4)*4+reg  [m89-verified]
#pragma unroll
  for (int nt = 0; nt < 4; ++nt) {
    const long col = col0 + wc + nt * 16 + lm;
    const float bc = bias[col];
#pragma unroll
    for (int mt = 0; mt < 4; ++mt) {
#pragma unroll
      for (int r = 0; r < 4; ++r) {
        const long row = row0 + wr + mt * 16 + lq * 4 + r;
        C[row * (long)ldc + col] = (OutT)(acc[mt][nt][r] + bc);
      }
    }
  }
}

// fused projection GEMM: cols [0,512)->qkv[:, :512] (ld 1024),
// [512,1024)->vg, [1024,1536)->qg, [1536,2048)->kg (ld 512)
__global__ __launch_bounds__(256, 2)
void gemm_proj(const bf16_t* __restrict__ A, const bf16_t* __restrict__ Wcat,
               const float* __restrict__ bcat, bf16_t* __restrict__ qkv,
               bf16_t* __restrict__ vg, bf16_t* __restrict__ qg,
               bf16_t* __restrict__ kg) {
  GEMM_CORE(A, Wcat)
  bf16_t* dst; long ld, cofs;
  if (col0 < 512)       { dst = qkv; ld = 1024; cofs = 0; }
  else if (col0 < 1024) { dst = vg;  ld = 512;  cofs = 512; }
  else if (col0 < 1536) { dst = qg;  ld = 512;  cofs = 1024; }
  else                  { dst = kg;  ld = 512;  cofs = 1536; }
#pragma unroll
  for (int nt = 0; nt < 4; ++nt) {
    const long col = col0 + wc + nt * 16 + lm;
    const float bc = bcat[col];
    const long cl = col - cofs;
#pragma unroll
    for (int mt = 0; mt < 4; ++mt) {
#pragma unroll
      for (int r = 0; r < 4; ++r) {
        const long row = row0 + wr + mt * 16 + lq * 4 + r;
        dst[row * ld + cl] = (bf16_t)(acc[mt][nt][r] + bc);
      }
    }
  }
}

// ---------------------------------------------------------------------------
// Sparse attention for global heads. Block = (qt, h, b): 64 query rows,
// 256 selected keys: token(l) = 64*(l>>2) + 32 + 4*h + (l&3).
// 4 waves x 16 query rows each. QK^T and PV via 16x16x32 bf16 MFMA.
// ---------------------------------------------------------------------------
__global__ __launch_bounds__(256, 1)
void attn_sparse(const bf16_t* __restrict__ qg, const bf16_t* __restrict__ kg,
                 const bf16_t* __restrict__ vg, const int* __restrict__ mask,
                 bf16_t* __restrict__ qkv) {
  __shared__ bf16_t Ks[16384];        // frag-order: chunk = kq*256 + lkey
  __shared__ bf16_t Vt[64 * 264];     // Vt[d][lkey], row stride 264 (+8 pad)
  __shared__ bf16_t Ps[4 * 16 * 136]; // per-wave P half-tile, stride 136 (+8 pad)
  __shared__ int smask[256];

  const int tid = threadIdx.x;
  const int b = blockIdx.z, h = blockIdx.y, qt = blockIdx.x;

  {
    const int lk = tid;  // key slot 0..255
    const int token = ((lk >> 2) << 6) + 32 + (h << 2) + (lk & 3);
    const size_t rowi = (size_t)(b * 4096 + token);
    const uint4* ksrc = (const uint4*)(kg + rowi * 512 + h * 64);
#pragma unroll
    for (int kq = 0; kq < 8; ++kq)
      *(uint4*)(Ks + (kq * 256 + lk) * 8) = ksrc[kq];
    const bf16_t* vsrc = vg + rowi * 512 + h * 64;
#pragma unroll
    for (int i = 0; i < 8; ++i) {
      bf16x8 vv = *(const bf16x8*)(vsrc + i * 8);
#pragma unroll
      for (int j = 0; j < 8; ++j) Vt[(i * 8 + j) * 264 + lk] = vv[j];
    }
    smask[lk] = mask[b * 4096 + token];
  }
  __syncthreads();

  const int w = tid >> 6, l = tid & 63, lq = l >> 4, lm = l & 15;
  const int mrow = (qt << 6) + (w << 4);

  const bf16_t* qrow = qg + (size_t)(b * 4096 + mrow + lm) * 512 + h * 64 + lq * 8;
  bf16x8 aq0 = *(const bf16x8*)qrow;
  bf16x8 aq1 = *(const bf16x8*)(qrow + 32);

  floatx4 zero4 = {0.f, 0.f, 0.f, 0.f};
  floatx4 s[16];
#pragma unroll
  for (int t = 0; t < 16; ++t) {
    bf16x8 kb0 = *(const bf16x8*)(Ks + (lq * 256 + t * 16 + lm) * 8);
    bf16x8 kb1 = *(const bf16x8*)(Ks + ((4 + lq) * 256 + t * 16 + lm) * 8);
    floatx4 z = zero4;
    z = MFMA16(aq0, kb0, z);
    z = MFMA16(aq1, kb1, z);
    s[t] = z;
  }

  float rmax[4] = {-1e30f, -1e30f, -1e30f, -1e30f};
#pragma unroll
  for (int t = 0; t < 16; ++t) {
    const bool mk = smask[t * 16 + lm] != 0;
#pragma unroll
    for (int r = 0; r < 4; ++r) {
      float v = s[t][r] * 0.125f;
      v = mk ? -1e10f : v;
      s[t][r] = v;
      rmax[r] = fmaxf(rmax[r], v);
    }
  }
#pragma unroll
  for (int off = 1; off < 16; off <<= 1)
#pragma unroll
    for (int r = 0; r < 4; ++r) rmax[r] = fmaxf(rmax[r], __shfl_xor(rmax[r], off));
  float rsum[4] = {0.f, 0.f, 0.f, 0.f};
#pragma unroll
  for (int t = 0; t < 16; ++t)
#pragma unroll
    for (int r = 0; r < 4; ++r) {
      float p = __expf(s[t][r] - rmax[r]);
      s[t][r] = p;
      rsum[r] += p;
    }
#pragma unroll
  for (int off = 1; off < 16; off <<= 1)
#pragma unroll
    for (int r = 0; r < 4; ++r) rsum[r] += __shfl_xor(rsum[r], off);
  float rinv[4];
#pragma unroll
  for (int r = 0; r < 4; ++r) rinv[r] = 1.0f / rsum[r];

  floatx4 o[4];
#pragma unroll
  for (int dt = 0; dt < 4; ++dt) o[dt] = zero4;
  bf16_t* Pw = Ps + w * (16 * 136);
#pragma unroll
  for (int half = 0; half < 2; ++half) {
#pragma unroll
    for (int t = 0; t < 8; ++t) {
      const int tt = half * 8 + t;
#pragma unroll
      for (int r = 0; r < 4; ++r)
        Pw[(lq * 4 + r) * 136 + t * 16 + lm] = (bf16_t)(s[tt][r] * rinv[r]);
    }
    __syncthreads();
#pragma unroll
    for (int ks = 0; ks < 4; ++ks) {
      bf16x8 pa = *(const bf16x8*)(Pw + lm * 136 + ks * 32 + lq * 8);
#pragma unroll
      for (int dt = 0; dt < 4; ++dt) {
        bf16x8 vb = *(const bf16x8*)(Vt + (dt * 16 + lm) * 264 + half * 128 + ks * 32 + lq * 8);
        o[dt] = MFMA16(pa, vb, o[dt]);
      }
    }
    __syncthreads();
  }

#pragma unroll
  for (int dt = 0; dt < 4; ++dt) {
    const int d = dt * 16 + lm;
#pragma unroll
    for (int r = 0; r < 4; ++r) {
      const int token = mrow + lq * 4 + r;
      qkv[(size_t)(b * 4096 + token) * 1024 + 512 + h * 64 + d] = (bf16_t)o[dt][r];
    }
  }
}

// ---------------------------------------------------------------------------
extern "C" void kernel_launch(void* const* d_in, const int* in_sizes, int n_in,
                              void* d_out, int out_size, void* d_ws, size_t ws_size,
                              hipStream_t stream) {
  const float* x   = (const float*)d_in[0];
  const int* mask  = (const int*)d_in[1];
  const float* Wq  = (const float*)d_in[2];
  const float* bq  = (const float*)d_in[3];
  const float* Wk  = (const float*)d_in[4];
  const float* bk  = (const float*)d_in[5];
  const float* Wv  = (const float*)d_in[6];
  const float* bv  = (const float*)d_in[7];
  const float* Wo  = (const float*)d_in[8];
  const float* bo  = (const float*)d_in[9];
  float* out = (float*)d_out;

  // ws: xb 32MB | Wcat 4MB | Wob 2MB | bcat 8KB | vg 16 | qg 16 | kg 16 | qkv 32
  char* ws = (char*)d_ws;
  bf16_t* xb   = (bf16_t*)(ws);
  bf16_t* Wcat = (bf16_t*)(ws + 33554432L);
  bf16_t* Wob  = (bf16_t*)(ws + 37748736L);
  float*  bcat = (float*)(ws + 39845888L);
  bf16_t* vg   = (bf16_t*)(ws + 39854080L);
  bf16_t* qg   = (bf16_t*)(ws + 56631296L);
  bf16_t* kg   = (bf16_t*)(ws + 73408512L);
  bf16_t* qkv  = (bf16_t*)(ws + 90185728L);

  dim3 blk(256);
  cvt_f32_bf16<<<16384, blk, 0, stream>>>(x, xb, 16777216);
  cvt_f32_bf16<<<1024, blk, 0, stream>>>(Wv, Wcat, 1048576);                    // rows 0..1023
  cvt_f32_bf16<<<512, blk, 0, stream>>>(Wq + 524288, Wcat + 1048576, 524288);   // rows 1024..1535
  cvt_f32_bf16<<<512, blk, 0, stream>>>(Wk + 524288, Wcat + 1572864, 524288);   // rows 1536..2047
  cvt_f32_bf16<<<1024, blk, 0, stream>>>(Wo, Wob, 1048576);
  pack_bias<<<8, blk, 0, stream>>>(bv, bq, bk, bcat);

  gemm_proj<<<dim3(16, 128), blk, 0, stream>>>(xb, Wcat, bcat, qkv, vg, qg, kg);
  attn_sparse<<<dim3(64, 8, 4), blk, 0, stream>>>(qg, kg, vg, mask, qkv);
  gemm_bt<float><<<dim3(8, 128), blk, 0, stream>>>(qkv, Wob, bo, out, 1024);
}

// Round 5
// 411.526 us; speedup vs baseline: 1.0709x; 1.0321x over previous
//
#include <hip/hip_runtime.h>
#include <stdint.h>

// ---------------------------------------------------------------------------
// Sparse attention, MI355X. f32 I/O, bf16 MFMA internals.
//   0) xb = bf16(x); Wcat = bf16([Wv; Wq[512:]; Wk[512:]]); Wob = bf16(Wo)
//   1) fused proj GEMM: [qkv[:,:512] | vg | qg | kg] = xb @ Wcat^T + bcat
//   2) qkv[:, 512:] = sparse_attention(qg, kg, vg, mask)
//   3) out(f32) = qkv @ Wob^T + bo
// GEMMs: global_load_lds width-16 DMA staging (m97 path) + XCD-aware block
// swizzle: each XCD owns a 16-row-tile band x all col tiles, so A-band (4MB)
// and W k-slices live in that XCD's L2 and are reused 16x/8x.
// ---------------------------------------------------------------------------

typedef __bf16 bf16_t;
typedef __bf16 bf16x4 __attribute__((ext_vector_type(4)));
typedef __bf16 bf16x8 __attribute__((ext_vector_type(8)));
typedef float floatx4 __attribute__((ext_vector_type(4)));

#define MFMA16(a, b, c) __builtin_amdgcn_mfma_f32_16x16x32_bf16((a), (b), (c), 0, 0, 0)

// async global->LDS, 16B per lane; LDS dest = wave-uniform base + lane*16
__device__ __forceinline__ void glds16(const bf16_t* g, const bf16_t* lds_base) {
  __builtin_amdgcn_global_load_lds(
      (const __attribute__((address_space(1))) uint32_t*)(uintptr_t)g,
      (__attribute__((address_space(3))) uint32_t*)(uintptr_t)lds_base, 16, 0, 0);
}

// ---------------------------------------------------------------------------
__global__ void cvt_f32_bf16(const float* __restrict__ src, bf16_t* __restrict__ dst, int n) {
  const int i = (blockIdx.x * 256 + threadIdx.x) * 4;
  if (i < n) {
    float4 v = *(const float4*)(src + i);
    bf16x4 d = {(bf16_t)v.x, (bf16_t)v.y, (bf16_t)v.z, (bf16_t)v.w};
    *(bf16x4*)(dst + i) = d;
  }
}

// bcat = [bv(1024); bq[512:](512); bk[512:](512)]  (f32, 2048)
__global__ void pack_bias(const float* __restrict__ bv, const float* __restrict__ bq,
                          const float* __restrict__ bk, float* __restrict__ bcat) {
  const int i = blockIdx.x * 256 + threadIdx.x;  // 2048 threads
  float v;
  if (i < 1024) v = bv[i];
  else if (i < 1536) v = bq[i - 512];
  else v = bk[i - 1024];
  bcat[i] = v;
}

// ---------------------------------------------------------------------------
// GEMM core. A: (M x 1024) bf16, W: (N x 1024) bf16 K-contiguous.
// 128x128 tile, BK=32, 4 waves each 64x64.  LDS frag order: chunk = q*128+m.
// ROW0_/COL0_ supplied by caller (XCD swizzle).
// ---------------------------------------------------------------------------
#define GEMM_CORE(A_, W_, ROW0_, COL0_)                                        \
  __shared__ bf16_t As[4096];                                                  \
  __shared__ bf16_t Bs[4096];                                                  \
  const int tid = threadIdx.x;                                                 \
  const int w = tid >> 6, l = tid & 63;                                        \
  const int lq = l >> 4, lm = l & 15;                                          \
  const long row0 = (ROW0_);                                                   \
  const long col0 = (COL0_);                                                   \
  const int wr = (w >> 1) << 6;                                                \
  const int wc = (w & 1) << 6;                                                 \
  floatx4 zero4 = {0.f, 0.f, 0.f, 0.f};                                        \
  floatx4 acc[4][4];                                                           \
  _Pragma("unroll") for (int i = 0; i < 4; ++i)                                \
      _Pragma("unroll") for (int j = 0; j < 4; ++j) acc[i][j] = zero4;         \
  const int id0 = w * 64 + l;                                                  \
  const int id1 = id0 + 256;                                                   \
  const int q0 = id0 >> 7, m0 = id0 & 127;                                     \
  const int q1 = id1 >> 7, m1 = id1 & 127;                                     \
  const bf16_t* ga0 = (A_) + (row0 + m0) * 1024 + q0 * 8;                      \
  const bf16_t* ga1 = (A_) + (row0 + m1) * 1024 + q1 * 8;                      \
  const bf16_t* gb0 = (W_) + (col0 + m0) * 1024 + q0 * 8;                      \
  const bf16_t* gb1 = (W_) + (col0 + m1) * 1024 + q1 * 8;                      \
  const bf16_t* lA0 = As + (w * 64) * 8;                                       \
  const bf16_t* lA1 = As + (256 + w * 64) * 8;                                 \
  const bf16_t* lB0 = Bs + (w * 64) * 8;                                       \
  const bf16_t* lB1 = Bs + (256 + w * 64) * 8;                                 \
  for (int kt = 0; kt < 32; ++kt) {                                            \
    glds16(ga0, lA0);                                                          \
    glds16(ga1, lA1);                                                          \
    glds16(gb0, lB0);                                                          \
    glds16(gb1, lB1);                                                          \
    ga0 += 32; ga1 += 32; gb0 += 32; gb1 += 32;                                \
    __syncthreads();                                                           \
    bf16x8 af[4], bfr[4];                                                      \
    _Pragma("unroll") for (int mt = 0; mt < 4; ++mt)                           \
        af[mt] = *(const bf16x8*)(As + (lq * 128 + wr + mt * 16 + lm) * 8);    \
    _Pragma("unroll") for (int nt = 0; nt < 4; ++nt)                           \
        bfr[nt] = *(const bf16x8*)(Bs + (lq * 128 + wc + nt * 16 + lm) * 8);   \
    _Pragma("unroll") for (int mt = 0; mt < 4; ++mt)                           \
        _Pragma("unroll") for (int nt = 0; nt < 4; ++nt)                       \
            acc[mt][nt] = MFMA16(af[mt], bfr[nt], acc[mt][nt]);                \
    __syncthreads();                                                           \
  }

// out-projection GEMM (8 col-tiles), XCD swizzle: xcd = n&7 owns rows
// [xcd*16, xcd*16+16) x all 8 cols.
template <typename OutT>
__global__ __launch_bounds__(256, 2)
void gemm_bt(const bf16_t* __restrict__ A, const bf16_t* __restrict__ W,
             const float* __restrict__ bias, OutT* __restrict__ C, int ldc) {
  const int n = blockIdx.x, xcd = n & 7, m = n >> 3;  // m in [0,128)
  GEMM_CORE(A, W, (long)((xcd << 4) | (m >> 3)) * 128, (long)(m & 7) * 128)
#pragma unroll
  for (int nt = 0; nt < 4; ++nt) {
    const long col = col0 + wc + nt * 16 + lm;
    const float bc = bias[col];
#pragma unroll
    for (int mt = 0; mt < 4; ++mt) {
#pragma unroll
      for (int r = 0; r < 4; ++r) {
        const long row = row0 + wr + mt * 16 + lq * 4 + r;
        C[row * (long)ldc + col] = (OutT)(acc[mt][nt][r] + bc);
      }
    }
  }
}

// fused projection GEMM (16 col-tiles), XCD swizzle: xcd = n&7 owns rows
// [xcd*16, xcd*16+16) x all 16 cols. cols [0,512)->qkv, [512,1024)->vg,
// [1024,1536)->qg, [1536,2048)->kg
__global__ __launch_bounds__(256, 2)
void gemm_proj(const bf16_t* __restrict__ A, const bf16_t* __restrict__ Wcat,
               const float* __restrict__ bcat, bf16_t* __restrict__ qkv,
               bf16_t* __restrict__ vg, bf16_t* __restrict__ qg,
               bf16_t* __restrict__ kg) {
  const int n = blockIdx.x, xcd = n & 7, m = n >> 3;  // m in [0,256)
  GEMM_CORE(A, Wcat, (long)((xcd << 4) | (m >> 4)) * 128, (long)(m & 15) * 128)
  bf16_t* dst; long ld, cofs;
  if (col0 < 512)       { dst = qkv; ld = 1024; cofs = 0; }
  else if (col0 < 1024) { dst = vg;  ld = 512;  cofs = 512; }
  else if (col0 < 1536) { dst = qg;  ld = 512;  cofs = 1024; }
  else                  { dst = kg;  ld = 512;  cofs = 1536; }
#pragma unroll
  for (int nt = 0; nt < 4; ++nt) {
    const long col = col0 + wc + nt * 16 + lm;
    const float bc = bcat[col];
    const long cl = col - cofs;
#pragma unroll
    for (int mt = 0; mt < 4; ++mt) {
#pragma unroll
      for (int r = 0; r < 4; ++r) {
        const long row = row0 + wr + mt * 16 + lq * 4 + r;
        dst[row * ld + cl] = (bf16_t)(acc[mt][nt][r] + bc);
      }
    }
  }
}

// ---------------------------------------------------------------------------
// Sparse attention for global heads. Block = (qt, h, b): 64 query rows,
// 256 selected keys: token(l) = 64*(l>>2) + 32 + 4*h + (l&3).
// ---------------------------------------------------------------------------
__global__ __launch_bounds__(256, 1)
void attn_sparse(const bf16_t* __restrict__ qg, const bf16_t* __restrict__ kg,
                 const bf16_t* __restrict__ vg, const int* __restrict__ mask,
                 bf16_t* __restrict__ qkv) {
  __shared__ bf16_t Ks[16384];        // frag-order: chunk = kq*256 + lkey
  __shared__ bf16_t Vt[64 * 264];     // Vt[d][lkey], row stride 264 (+8 pad)
  __shared__ bf16_t Ps[4 * 16 * 136]; // per-wave P half-tile, stride 136 (+8 pad)
  __shared__ int smask[256];

  const int tid = threadIdx.x;
  const int b = blockIdx.z, h = blockIdx.y, qt = blockIdx.x;

  {
    const int lk = tid;
    const int token = ((lk >> 2) << 6) + 32 + (h << 2) + (lk & 3);
    const size_t rowi = (size_t)(b * 4096 + token);
    const uint4* ksrc = (const uint4*)(kg + rowi * 512 + h * 64);
#pragma unroll
    for (int kq = 0; kq < 8; ++kq)
      *(uint4*)(Ks + (kq * 256 + lk) * 8) = ksrc[kq];
    const bf16_t* vsrc = vg + rowi * 512 + h * 64;
#pragma unroll
    for (int i = 0; i < 8; ++i) {
      bf16x8 vv = *(const bf16x8*)(vsrc + i * 8);
#pragma unroll
      for (int j = 0; j < 8; ++j) Vt[(i * 8 + j) * 264 + lk] = vv[j];
    }
    smask[lk] = mask[b * 4096 + token];
  }
  __syncthreads();

  const int w = tid >> 6, l = tid & 63, lq = l >> 4, lm = l & 15;
  const int mrow = (qt << 6) + (w << 4);

  const bf16_t* qrow = qg + (size_t)(b * 4096 + mrow + lm) * 512 + h * 64 + lq * 8;
  bf16x8 aq0 = *(const bf16x8*)qrow;
  bf16x8 aq1 = *(const bf16x8*)(qrow + 32);

  floatx4 zero4 = {0.f, 0.f, 0.f, 0.f};
  floatx4 s[16];
#pragma unroll
  for (int t = 0; t < 16; ++t) {
    bf16x8 kb0 = *(const bf16x8*)(Ks + (lq * 256 + t * 16 + lm) * 8);
    bf16x8 kb1 = *(const bf16x8*)(Ks + ((4 + lq) * 256 + t * 16 + lm) * 8);
    floatx4 z = zero4;
    z = MFMA16(aq0, kb0, z);
    z = MFMA16(aq1, kb1, z);
    s[t] = z;
  }

  float rmax[4] = {-1e30f, -1e30f, -1e30f, -1e30f};
#pragma unroll
  for (int t = 0; t < 16; ++t) {
    const bool mk = smask[t * 16 + lm] != 0;
#pragma unroll
    for (int r = 0; r < 4; ++r) {
      float v = s[t][r] * 0.125f;
      v = mk ? -1e10f : v;
      s[t][r] = v;
      rmax[r] = fmaxf(rmax[r], v);
    }
  }
#pragma unroll
  for (int off = 1; off < 16; off <<= 1)
#pragma unroll
    for (int r = 0; r < 4; ++r) rmax[r] = fmaxf(rmax[r], __shfl_xor(rmax[r], off));
  float rsum[4] = {0.f, 0.f, 0.f, 0.f};
#pragma unroll
  for (int t = 0; t < 16; ++t)
#pragma unroll
    for (int r = 0; r < 4; ++r) {
      float p = __expf(s[t][r] - rmax[r]);
      s[t][r] = p;
      rsum[r] += p;
    }
#pragma unroll
  for (int off = 1; off < 16; off <<= 1)
#pragma unroll
    for (int r = 0; r < 4; ++r) rsum[r] += __shfl_xor(rsum[r], off);
  float rinv[4];
#pragma unroll
  for (int r = 0; r < 4; ++r) rinv[r] = 1.0f / rsum[r];

  floatx4 o[4];
#pragma unroll
  for (int dt = 0; dt < 4; ++dt) o[dt] = zero4;
  bf16_t* Pw = Ps + w * (16 * 136);
#pragma unroll
  for (int half = 0; half < 2; ++half) {
#pragma unroll
    for (int t = 0; t < 8; ++t) {
      const int tt = half * 8 + t;
#pragma unroll
      for (int r = 0; r < 4; ++r)
        Pw[(lq * 4 + r) * 136 + t * 16 + lm] = (bf16_t)(s[tt][r] * rinv[r]);
    }
    __syncthreads();
#pragma unroll
    for (int ks = 0; ks < 4; ++ks) {
      bf16x8 pa = *(const bf16x8*)(Pw + lm * 136 + ks * 32 + lq * 8);
#pragma unroll
      for (int dt = 0; dt < 4; ++dt) {
        bf16x8 vb = *(const bf16x8*)(Vt + (dt * 16 + lm) * 264 + half * 128 + ks * 32 + lq * 8);
        o[dt] = MFMA16(pa, vb, o[dt]);
      }
    }
    __syncthreads();
  }

#pragma unroll
  for (int dt = 0; dt < 4; ++dt) {
    const int d = dt * 16 + lm;
#pragma unroll
    for (int r = 0; r < 4; ++r) {
      const int token = mrow + lq * 4 + r;
      qkv[(size_t)(b * 4096 + token) * 1024 + 512 + h * 64 + d] = (bf16_t)o[dt][r];
    }
  }
}

// ---------------------------------------------------------------------------
extern "C" void kernel_launch(void* const* d_in, const int* in_sizes, int n_in,
                              void* d_out, int out_size, void* d_ws, size_t ws_size,
                              hipStream_t stream) {
  const float* x   = (const float*)d_in[0];
  const int* mask  = (const int*)d_in[1];
  const float* Wq  = (const float*)d_in[2];
  const float* bq  = (const float*)d_in[3];
  const float* Wk  = (const float*)d_in[4];
  const float* bk  = (const float*)d_in[5];
  const float* Wv  = (const float*)d_in[6];
  const float* bv  = (const float*)d_in[7];
  const float* Wo  = (const float*)d_in[8];
  const float* bo  = (const float*)d_in[9];
  float* out = (float*)d_out;

  // ws: xb 32MB | Wcat 4MB | Wob 2MB | bcat 8KB | vg 16 | qg 16 | kg 16 | qkv 32
  char* ws = (char*)d_ws;
  bf16_t* xb   = (bf16_t*)(ws);
  bf16_t* Wcat = (bf16_t*)(ws + 33554432L);
  bf16_t* Wob  = (bf16_t*)(ws + 37748736L);
  float*  bcat = (float*)(ws + 39845888L);
  bf16_t* vg   = (bf16_t*)(ws + 39854080L);
  bf16_t* qg   = (bf16_t*)(ws + 56631296L);
  bf16_t* kg   = (bf16_t*)(ws + 73408512L);
  bf16_t* qkv  = (bf16_t*)(ws + 90185728L);

  dim3 blk(256);
  cvt_f32_bf16<<<16384, blk, 0, stream>>>(x, xb, 16777216);
  cvt_f32_bf16<<<1024, blk, 0, stream>>>(Wv, Wcat, 1048576);
  cvt_f32_bf16<<<512, blk, 0, stream>>>(Wq + 524288, Wcat + 1048576, 524288);
  cvt_f32_bf16<<<512, blk, 0, stream>>>(Wk + 524288, Wcat + 1572864, 524288);
  cvt_f32_bf16<<<1024, blk, 0, stream>>>(Wo, Wob, 1048576);
  pack_bias<<<8, blk, 0, stream>>>(bv, bq, bk, bcat);

  gemm_proj<<<2048, blk, 0, stream>>>(xb, Wcat, bcat, qkv, vg, qg, kg);
  attn_sparse<<<dim3(64, 8, 4), blk, 0, stream>>>(qg, kg, vg, mask, qkv);
  gemm_bt<float><<<1024, blk, 0, stream>>>(qkv, Wob, bo, out, 1024);
}